// Round 13
// baseline (565.172 us; speedup 1.0000x reference)
//
#include <hip/hip_runtime.h>
#include <hip/hip_bf16.h>

#define N 16384
#define D 128
#define RS 32                        // row splits (512 rows each)
#define CT 32                        // col tiles (N / 512)
#define ROWS_PER_SPLIT (N / RS)      // 512
#define ITERS (ROWS_PER_SPLIT / 32)  // 16 iterations of 32 rows

typedef __attribute__((ext_vector_type(16))) float f32x16;
typedef long long i64;
typedef __attribute__((ext_vector_type(2))) long long i64x2;

// ---------------- Kernel A: normalize targets -> fp8 e4m3, fragment-permuted ----------------
// For 32x32x16 fp8 MFMA: lane l holds row/col (l&31), k = ks*16 + (l>>5)*8 + j.
// Store byte (row,k) at row*128 + ((k>>3)&1)*64 + (k>>4)*8 + (k&7): each lane's
// whole 8-MFMA fragment (64 bytes) is contiguous.
__global__ __launch_bounds__(256) void knorm(const float* __restrict__ t,
                                             unsigned char* __restrict__ bnq) {
    const int row  = blockIdx.x * 4 + (threadIdx.x >> 6);
    const int lane = threadIdx.x & 63;
    const float2 v = *(const float2*)(t + (size_t)row * D + lane * 2);
    float ss = v.x * v.x + v.y * v.y;
#pragma unroll
    for (int m = 1; m <= 32; m <<= 1) ss += __shfl_xor(ss, m, 64);
    const float inv = rsqrtf(ss);
    const int k   = lane * 2;
    const int off = ((k >> 3) & 1) * 64 + (k >> 4) * 8 + (k & 7);
    const unsigned bits =
        (unsigned)__builtin_amdgcn_cvt_pk_fp8_f32(v.x * inv, v.y * inv, 0, false);
    *(unsigned short*)(bnq + (size_t)row * 128 + off) = (unsigned short)(bits & 0xFFFFu);
}

// ---------------- Kernel B: fused fp8 bn @ bn^T (32x32x16) + group-argmax ----------------
// R12 structure, doubled grid: 1024 blocks (4/CU -> 4 waves/SIMD) x 4 waves.
// Wave w: cols [ct*512 + w*128, +128) persistent in fb[4][8] (64 VGPRs);
// rows [s*512,(s+1)*512) streamed double-buffered, no LDS, no barriers.
// Decode: XCD x = b&7 gets splits x*4..x*4+3; 4 blocks/CU share one split
// (i stride 32 == 0 mod 4) -> same A-stream, L1/L2 dedup.
__global__ __launch_bounds__(256, 4) void kargmax(const unsigned char* __restrict__ bnq,
                                                  float* __restrict__ pval,
                                                  int* __restrict__ pcode) {
    const int tid  = threadIdx.x;
    const int lane = tid & 63;
    const int w    = tid >> 6;
    const int b    = blockIdx.x;
    const int x    = b & 7;
    const int i    = b >> 3;                  // 0..127
    const int s    = x * 4 + (i & 3);         // 0..31, 4 splits per XCD
    const int ct   = i >> 2;                  // 0..31
    const int j0w  = ct * 512 + w * 128;
    const int rbase = s * ROWS_PER_SPLIT;

    const int cl = lane & 31;      // row/col within 32
    const int hi = lane >> 5;      // k-half
    const int rloc = cl - 4 * hi;  // diag helper: diag when rloc == (r&3)+8*(r>>2)

    // persistent B fragments: 128 cols x 128 K, fp8 (4 col-tiles x 8 K-steps, 64 VGPRs)
    i64 fb[4][8];
#pragma unroll
    for (int c4 = 0; c4 < 4; ++c4)
#pragma unroll
        for (int ks = 0; ks < 8; ++ks)
            fb[c4][ks] = *(const i64*)(bnq + (size_t)(j0w + c4 * 32 + cl) * 128 +
                                       hi * 64 + ks * 8);

    const unsigned char* aptr = bnq + (size_t)(rbase + cl) * 128 + hi * 64;

    float mv[4];
#pragma unroll
    for (int c4 = 0; c4 < 4; ++c4) mv[c4] = -1e30f;
    unsigned gb = (unsigned)hi;        // gid = gb + 2*g; gb += 8 per iter (max 127)

    const f32x16 z16 = {0.f,0.f,0.f,0.f,0.f,0.f,0.f,0.f,0.f,0.f,0.f,0.f,0.f,0.f,0.f,0.f};
    i64x2 fA[4], fB[4];

#define LOADF(buf, itv) do {                                  \
    const unsigned char* p_ = aptr + (size_t)(itv) * 4096;    \
    buf[0] = *(const i64x2*)(p_);                             \
    buf[1] = *(const i64x2*)(p_ + 16);                        \
    buf[2] = *(const i64x2*)(p_ + 32);                        \
    buf[3] = *(const i64x2*)(p_ + 48); } while (0)

#define COMPUTEF(buf, itv) do {                                                             \
    const int r0_ = rbase + (itv) * 32;                                                     \
    const bool dg_ = ((unsigned)(r0_ - j0w) < 128u);                                        \
    _Pragma("unroll")                                                                       \
    for (int c4 = 0; c4 < 4; ++c4) {                                                        \
        f32x16 acc;                                                                         \
        __builtin_amdgcn_s_setprio(1);                                                      \
        acc = __builtin_amdgcn_mfma_f32_32x32x16_fp8_fp8(buf[0][0], fb[c4][0], z16, 0, 0, 0); \
        acc = __builtin_amdgcn_mfma_f32_32x32x16_fp8_fp8(buf[0][1], fb[c4][1], acc, 0, 0, 0); \
        acc = __builtin_amdgcn_mfma_f32_32x32x16_fp8_fp8(buf[1][0], fb[c4][2], acc, 0, 0, 0); \
        acc = __builtin_amdgcn_mfma_f32_32x32x16_fp8_fp8(buf[1][1], fb[c4][3], acc, 0, 0, 0); \
        acc = __builtin_amdgcn_mfma_f32_32x32x16_fp8_fp8(buf[2][0], fb[c4][4], acc, 0, 0, 0); \
        acc = __builtin_amdgcn_mfma_f32_32x32x16_fp8_fp8(buf[2][1], fb[c4][5], acc, 0, 0, 0); \
        acc = __builtin_amdgcn_mfma_f32_32x32x16_fp8_fp8(buf[3][0], fb[c4][6], acc, 0, 0, 0); \
        acc = __builtin_amdgcn_mfma_f32_32x32x16_fp8_fp8(buf[3][1], fb[c4][7], acc, 0, 0, 0); \
        __builtin_amdgcn_s_setprio(0);                                                      \
        if (dg_ && r0_ == j0w + c4 * 32) {                                                  \
            _Pragma("unroll")                                                               \
            for (int r = 0; r < 16; ++r)                                                    \
                if (rloc == ((r & 3) + 8 * (r >> 2))) acc[r] -= 1.0f;                       \
        }                                                                                   \
        _Pragma("unroll")                                                                   \
        for (int g = 0; g < 4; ++g) {                                                       \
            const float g_ = fmaxf(fmaxf(acc[4*g], acc[4*g+1]),                             \
                                   fmaxf(acc[4*g+2], acc[4*g+3]));                          \
            const unsigned p_ = (__float_as_uint(g_) & 0xFFFFFF00u) | (gb + 2u * g);        \
            mv[c4] = fmaxf(mv[c4], __uint_as_float(p_));                                    \
        }                                                                                   \
    }                                                                                       \
    gb += 8u; } while (0)

    LOADF(fA, 0);
    LOADF(fB, 1);
    for (int it2 = 0; it2 < ITERS; it2 += 2) {
        COMPUTEF(fA, it2);     LOADF(fA, it2 + 2);   // overshoot -> pval pad, unused
        COMPUTEF(fB, it2 + 1); LOADF(fB, it2 + 3);
    }
#undef LOADF
#undef COMPUTEF

    // lanes l and l+32 share col cl: one packed fmax merges the k-halves
#pragma unroll
    for (int c4 = 0; c4 < 4; ++c4) {
        float v = mv[c4];
        v = fmaxf(v, __shfl_xor(v, 32, 64));
        if (lane < 32) {
            pval[(size_t)s * N + j0w + c4 * 32 + cl]  = v;
            pcode[(size_t)s * N + j0w + c4 * 32 + cl] =
                rbase + (int)(__float_as_uint(v) & 255u) * 4;
        }
    }
}

// ---------------- Kernel C: merge splits, re-rank 4 candidates in fp32, hinge ----------------
__global__ __launch_bounds__(256) void kloss(const float* __restrict__ q,
                                             const float* __restrict__ t,
                                             const float* __restrict__ pval,
                                             const int* __restrict__ pcode,
                                             float* __restrict__ bsum) {
    const int j    = blockIdx.x * 4 + (threadIdx.x >> 6);
    const int lane = threadIdx.x & 63;

    // merge the RS=32 split winners (lane s holds split s)
    float v = -1e30f;
    int   c = 0;
    if (lane < RS) { v = pval[(size_t)lane * N + j]; c = pcode[(size_t)lane * N + j]; }
#pragma unroll
    for (int m = 1; m <= 16; m <<= 1) {
        const float ov = __shfl_xor(v, m, 64);
        const int   oc = __shfl_xor(c, m, 64);
        if (ov > v || (ov == v && oc < c)) { v = ov; c = oc; }
    }
    c = __shfl(c, 0, 64);

    const float2 qv = *(const float2*)(q + (size_t)j * D + lane * 2);
    const float2 tv = *(const float2*)(t + (size_t)j * D + lane * 2);
    float qq = qv.x * qv.x + qv.y * qv.y;
    float tt = tv.x * tv.x + tv.y * tv.y;
    float qt = qv.x * tv.x + qv.y * tv.y;
    float ww[4], wt[4], qw[4];
#pragma unroll
    for (int r = 0; r < 4; ++r) {
        const float2 wv = *(const float2*)(t + (size_t)(c + r) * D + lane * 2);
        ww[r] = wv.x * wv.x + wv.y * wv.y;
        wt[r] = wv.x * tv.x + wv.y * tv.y;
        qw[r] = wv.x * qv.x + wv.y * qv.y;
    }
#pragma unroll
    for (int m = 1; m <= 32; m <<= 1) {
        qq += __shfl_xor(qq, m, 64);
        tt += __shfl_xor(tt, m, 64);
        qt += __shfl_xor(qt, m, 64);
#pragma unroll
        for (int r = 0; r < 4; ++r) {
            ww[r] += __shfl_xor(ww[r], m, 64);
            wt[r] += __shfl_xor(wt[r], m, 64);
            qw[r] += __shfl_xor(qw[r], m, 64);
        }
    }
    const float pos = qt * rsqrtf(qq * tt);
    float best = -1e30f, neg = 0.f;
#pragma unroll
    for (int r = 0; r < 4; ++r) {
        float cr = wt[r] * rsqrtf(ww[r] * tt);
        if (c + r == j) cr -= 1.0f;              // diag candidate, matches sim - eye
        if (cr > best) { best = cr; neg = qw[r] * rsqrtf(qq * ww[r]); }
    }
    const float l = fmaxf(0.f, 1.0f - pos + neg);

    __shared__ float ls[4];
    if (lane == 0) ls[threadIdx.x >> 6] = l;
    __syncthreads();
    if (threadIdx.x == 0) bsum[blockIdx.x] = ls[0] + ls[1] + ls[2] + ls[3];
}

// ---------------- Kernel D: deterministic final mean ----------------
__global__ __launch_bounds__(256) void kfinal(const float* __restrict__ bsum,
                                              float* __restrict__ out) {
    float sum = 0.f;
    for (int i = threadIdx.x; i < N / 4; i += 256) sum += bsum[i];
#pragma unroll
    for (int m = 1; m <= 32; m <<= 1) sum += __shfl_xor(sum, m, 64);
    __shared__ float ws2[4];
    if ((threadIdx.x & 63) == 0) ws2[threadIdx.x >> 6] = sum;
    __syncthreads();
    if (threadIdx.x == 0) out[0] = (ws2[0] + ws2[1] + ws2[2] + ws2[3]) * (1.0f / N);
}

extern "C" void kernel_launch(void* const* d_in, const int* in_sizes, int n_in,
                              void* d_out, int out_size, void* d_ws, size_t ws_size,
                              hipStream_t stream) {
    const float* q = (const float*)d_in[0];
    const float* t = (const float*)d_in[1];
    char* ws = (char*)d_ws;

    unsigned char* bnq = (unsigned char*)ws;                           // 2 MB (must stay first)
    float* pval = (float*)(ws + (size_t)N * 128);                      // 2 MB (also overshoot pad)
    int*   pcode = (int*)(ws + (size_t)N * 128 + (size_t)RS * N * 4);  // 2 MB
    float* bsum = (float*)(ws + (size_t)N * 128 + (size_t)2 * RS * N * 4); // 16 KB

    knorm<<<dim3(N / 4), dim3(256), 0, stream>>>(t, bnq);
    kargmax<<<dim3(CT * RS), dim3(256), 0, stream>>>(bnq, pval, pcode);
    kloss<<<dim3(N / 4), dim3(256), 0, stream>>>(q, t, pval, pcode, bsum);
    kfinal<<<dim3(1), dim3(256), 0, stream>>>(bsum, (float*)d_out);
}

// Round 14
// 83.312 us; speedup vs baseline: 6.7838x; 6.7838x over previous
//
#include <hip/hip_runtime.h>
#include <hip/hip_bf16.h>

#define N 16384
#define D 128
#define RS 32                        // row splits (512 rows each)
#define CT 32                        // col tiles (N / 512)
#define ROWS_PER_SPLIT (N / RS)      // 512
#define ITERS (ROWS_PER_SPLIT / 32)  // 16 iterations of 32 rows

typedef __attribute__((ext_vector_type(16))) float f32x16;
typedef long long i64;
typedef __attribute__((ext_vector_type(2))) long long i64x2;

// ---------------- Kernel A: normalize targets -> fp8 e4m3, fragment-permuted ----------------
// For 32x32x16 fp8 MFMA: lane l holds row/col (l&31), k = ks*16 + (l>>5)*8 + j.
// Store byte (row,k) at row*128 + ((k>>3)&1)*64 + (k>>4)*8 + (k&7): each lane's
// whole 8-MFMA fragment (64 bytes) is contiguous.
__global__ __launch_bounds__(256) void knorm(const float* __restrict__ t,
                                             unsigned char* __restrict__ bnq) {
    const int row  = blockIdx.x * 4 + (threadIdx.x >> 6);
    const int lane = threadIdx.x & 63;
    const float2 v = *(const float2*)(t + (size_t)row * D + lane * 2);
    float ss = v.x * v.x + v.y * v.y;
#pragma unroll
    for (int m = 1; m <= 32; m <<= 1) ss += __shfl_xor(ss, m, 64);
    const float inv = rsqrtf(ss);
    const int k   = lane * 2;
    const int off = ((k >> 3) & 1) * 64 + (k >> 4) * 8 + (k & 7);
    const unsigned bits =
        (unsigned)__builtin_amdgcn_cvt_pk_fp8_f32(v.x * inv, v.y * inv, 0, false);
    *(unsigned short*)(bnq + (size_t)row * 128 + off) = (unsigned short)(bits & 0xFFFFu);
}

// ---------------- Kernel B: fused fp8 bn @ bn^T (32x32x16) + group-argmax ----------------
// 1024 blocks x 4 waves; launch_bounds(256,2) — the (256,4) bound in R13 forced a
// 64-VGPR allocation and catastrophic spill. The compiler's natural ~120 VGPR fits
// 4 blocks/CU anyway (occupancy follows actual VGPR count, not the bound).
// Decode: XCD x = b&7 gets splits x*4..x*4+3; the 4 co-resident blocks per CU
// share one split (i stride 32 == 0 mod 4) -> same A-stream, L1/L2 dedup.
__global__ __launch_bounds__(256, 2) void kargmax(const unsigned char* __restrict__ bnq,
                                                  float* __restrict__ pval,
                                                  int* __restrict__ pcode) {
    const int tid  = threadIdx.x;
    const int lane = tid & 63;
    const int w    = tid >> 6;
    const int b    = blockIdx.x;
    const int x    = b & 7;
    const int i    = b >> 3;                  // 0..127
    const int s    = x * 4 + (i & 3);         // 0..31, 4 splits per XCD
    const int ct   = i >> 2;                  // 0..31
    const int j0w  = ct * 512 + w * 128;
    const int rbase = s * ROWS_PER_SPLIT;

    const int cl = lane & 31;      // row/col within 32
    const int hi = lane >> 5;      // k-half
    const int rloc = cl - 4 * hi;  // diag helper: diag when rloc == (r&3)+8*(r>>2)

    // persistent B fragments: 128 cols x 128 K, fp8 (4 col-tiles x 8 K-steps, 64 VGPRs)
    i64 fb[4][8];
#pragma unroll
    for (int c4 = 0; c4 < 4; ++c4)
#pragma unroll
        for (int ks = 0; ks < 8; ++ks)
            fb[c4][ks] = *(const i64*)(bnq + (size_t)(j0w + c4 * 32 + cl) * 128 +
                                       hi * 64 + ks * 8);

    const unsigned char* aptr = bnq + (size_t)(rbase + cl) * 128 + hi * 64;

    float mv[4];
#pragma unroll
    for (int c4 = 0; c4 < 4; ++c4) mv[c4] = -1e30f;
    unsigned gb = (unsigned)hi;        // gid = gb + 2*g; gb += 8 per iter (max 127)

    const f32x16 z16 = {0.f,0.f,0.f,0.f,0.f,0.f,0.f,0.f,0.f,0.f,0.f,0.f,0.f,0.f,0.f,0.f};
    i64x2 fA[4], fB[4];

#define LOADF(buf, itv) do {                                  \
    const unsigned char* p_ = aptr + (size_t)(itv) * 4096;    \
    buf[0] = *(const i64x2*)(p_);                             \
    buf[1] = *(const i64x2*)(p_ + 16);                        \
    buf[2] = *(const i64x2*)(p_ + 32);                        \
    buf[3] = *(const i64x2*)(p_ + 48); } while (0)

#define COMPUTEF(buf, itv) do {                                                             \
    const int r0_ = rbase + (itv) * 32;                                                     \
    const bool dg_ = ((unsigned)(r0_ - j0w) < 128u);                                        \
    _Pragma("unroll")                                                                       \
    for (int c4 = 0; c4 < 4; ++c4) {                                                        \
        f32x16 acc;                                                                         \
        __builtin_amdgcn_s_setprio(1);                                                      \
        acc = __builtin_amdgcn_mfma_f32_32x32x16_fp8_fp8(buf[0][0], fb[c4][0], z16, 0, 0, 0); \
        acc = __builtin_amdgcn_mfma_f32_32x32x16_fp8_fp8(buf[0][1], fb[c4][1], acc, 0, 0, 0); \
        acc = __builtin_amdgcn_mfma_f32_32x32x16_fp8_fp8(buf[1][0], fb[c4][2], acc, 0, 0, 0); \
        acc = __builtin_amdgcn_mfma_f32_32x32x16_fp8_fp8(buf[1][1], fb[c4][3], acc, 0, 0, 0); \
        acc = __builtin_amdgcn_mfma_f32_32x32x16_fp8_fp8(buf[2][0], fb[c4][4], acc, 0, 0, 0); \
        acc = __builtin_amdgcn_mfma_f32_32x32x16_fp8_fp8(buf[2][1], fb[c4][5], acc, 0, 0, 0); \
        acc = __builtin_amdgcn_mfma_f32_32x32x16_fp8_fp8(buf[3][0], fb[c4][6], acc, 0, 0, 0); \
        acc = __builtin_amdgcn_mfma_f32_32x32x16_fp8_fp8(buf[3][1], fb[c4][7], acc, 0, 0, 0); \
        __builtin_amdgcn_s_setprio(0);                                                      \
        if (dg_ && r0_ == j0w + c4 * 32) {                                                  \
            _Pragma("unroll")                                                               \
            for (int r = 0; r < 16; ++r)                                                    \
                if (rloc == ((r & 3) + 8 * (r >> 2))) acc[r] -= 1.0f;                       \
        }                                                                                   \
        _Pragma("unroll")                                                                   \
        for (int g = 0; g < 4; ++g) {                                                       \
            const float g_ = fmaxf(fmaxf(acc[4*g], acc[4*g+1]),                             \
                                   fmaxf(acc[4*g+2], acc[4*g+3]));                          \
            const unsigned p_ = (__float_as_uint(g_) & 0xFFFFFF00u) | (gb + 2u * g);        \
            mv[c4] = fmaxf(mv[c4], __uint_as_float(p_));                                    \
        }                                                                                   \
    }                                                                                       \
    gb += 8u; } while (0)

    LOADF(fA, 0);
    LOADF(fB, 1);
    for (int it2 = 0; it2 < ITERS; it2 += 2) {
        COMPUTEF(fA, it2);     LOADF(fA, it2 + 2);   // overshoot -> pval pad, unused
        COMPUTEF(fB, it2 + 1); LOADF(fB, it2 + 3);
    }
#undef LOADF
#undef COMPUTEF

    // lanes l and l+32 share col cl: one packed fmax merges the k-halves
#pragma unroll
    for (int c4 = 0; c4 < 4; ++c4) {
        float v = mv[c4];
        v = fmaxf(v, __shfl_xor(v, 32, 64));
        if (lane < 32) {
            pval[(size_t)s * N + j0w + c4 * 32 + cl]  = v;
            pcode[(size_t)s * N + j0w + c4 * 32 + cl] =
                rbase + (int)(__float_as_uint(v) & 255u) * 4;
        }
    }
}

// ---------------- Kernel C: merge splits, re-rank 4 candidates in fp32, hinge ----------------
__global__ __launch_bounds__(256) void kloss(const float* __restrict__ q,
                                             const float* __restrict__ t,
                                             const float* __restrict__ pval,
                                             const int* __restrict__ pcode,
                                             float* __restrict__ bsum) {
    const int j    = blockIdx.x * 4 + (threadIdx.x >> 6);
    const int lane = threadIdx.x & 63;

    // merge the RS=32 split winners (lane s holds split s)
    float v = -1e30f;
    int   c = 0;
    if (lane < RS) { v = pval[(size_t)lane * N + j]; c = pcode[(size_t)lane * N + j]; }
#pragma unroll
    for (int m = 1; m <= 16; m <<= 1) {
        const float ov = __shfl_xor(v, m, 64);
        const int   oc = __shfl_xor(c, m, 64);
        if (ov > v || (ov == v && oc < c)) { v = ov; c = oc; }
    }
    c = __shfl(c, 0, 64);

    const float2 qv = *(const float2*)(q + (size_t)j * D + lane * 2);
    const float2 tv = *(const float2*)(t + (size_t)j * D + lane * 2);
    float qq = qv.x * qv.x + qv.y * qv.y;
    float tt = tv.x * tv.x + tv.y * tv.y;
    float qt = qv.x * tv.x + qv.y * tv.y;
    float ww[4], wt[4], qw[4];
#pragma unroll
    for (int r = 0; r < 4; ++r) {
        const float2 wv = *(const float2*)(t + (size_t)(c + r) * D + lane * 2);
        ww[r] = wv.x * wv.x + wv.y * wv.y;
        wt[r] = wv.x * tv.x + wv.y * tv.y;
        qw[r] = wv.x * qv.x + wv.y * qv.y;
    }
#pragma unroll
    for (int m = 1; m <= 32; m <<= 1) {
        qq += __shfl_xor(qq, m, 64);
        tt += __shfl_xor(tt, m, 64);
        qt += __shfl_xor(qt, m, 64);
#pragma unroll
        for (int r = 0; r < 4; ++r) {
            ww[r] += __shfl_xor(ww[r], m, 64);
            wt[r] += __shfl_xor(wt[r], m, 64);
            qw[r] += __shfl_xor(qw[r], m, 64);
        }
    }
    const float pos = qt * rsqrtf(qq * tt);
    float best = -1e30f, neg = 0.f;
#pragma unroll
    for (int r = 0; r < 4; ++r) {
        float cr = wt[r] * rsqrtf(ww[r] * tt);
        if (c + r == j) cr -= 1.0f;              // diag candidate, matches sim - eye
        if (cr > best) { best = cr; neg = qw[r] * rsqrtf(qq * ww[r]); }
    }
    const float l = fmaxf(0.f, 1.0f - pos + neg);

    __shared__ float ls[4];
    if (lane == 0) ls[threadIdx.x >> 6] = l;
    __syncthreads();
    if (threadIdx.x == 0) bsum[blockIdx.x] = ls[0] + ls[1] + ls[2] + ls[3];
}

// ---------------- Kernel D: deterministic final mean ----------------
__global__ __launch_bounds__(256) void kfinal(const float* __restrict__ bsum,
                                              float* __restrict__ out) {
    float sum = 0.f;
    for (int i = threadIdx.x; i < N / 4; i += 256) sum += bsum[i];
#pragma unroll
    for (int m = 1; m <= 32; m <<= 1) sum += __shfl_xor(sum, m, 64);
    __shared__ float ws2[4];
    if ((threadIdx.x & 63) == 0) ws2[threadIdx.x >> 6] = sum;
    __syncthreads();
    if (threadIdx.x == 0) out[0] = (ws2[0] + ws2[1] + ws2[2] + ws2[3]) * (1.0f / N);
}

extern "C" void kernel_launch(void* const* d_in, const int* in_sizes, int n_in,
                              void* d_out, int out_size, void* d_ws, size_t ws_size,
                              hipStream_t stream) {
    const float* q = (const float*)d_in[0];
    const float* t = (const float*)d_in[1];
    char* ws = (char*)d_ws;

    unsigned char* bnq = (unsigned char*)ws;                           // 2 MB (must stay first)
    float* pval = (float*)(ws + (size_t)N * 128);                      // 2 MB (also overshoot pad)
    int*   pcode = (int*)(ws + (size_t)N * 128 + (size_t)RS * N * 4);  // 2 MB
    float* bsum = (float*)(ws + (size_t)N * 128 + (size_t)2 * RS * N * 4); // 16 KB

    knorm<<<dim3(N / 4), dim3(256), 0, stream>>>(t, bnq);
    kargmax<<<dim3(CT * RS), dim3(256), 0, stream>>>(bnq, pval, pcode);
    kloss<<<dim3(N / 4), dim3(256), 0, stream>>>(q, t, pval, pcode, bsum);
    kfinal<<<dim3(1), dim3(256), 0, stream>>>(bsum, (float*)d_out);
}

// Round 15
// 78.296 us; speedup vs baseline: 7.2184x; 1.0641x over previous
//
#include <hip/hip_runtime.h>
#include <hip/hip_bf16.h>

#define N 16384
#define D 128
#define RS 16                        // row splits (1024 rows each)
#define CT 32                        // col tiles (N / 512)
#define ROWS_PER_SPLIT (N / RS)      // 1024
#define ITERS (ROWS_PER_SPLIT / 32)  // 32 iterations of 32 rows

typedef __attribute__((ext_vector_type(16))) float f32x16;
typedef long long i64;
typedef __attribute__((ext_vector_type(2))) long long i64x2;

// ---------------- Kernel A: normalize targets -> fp8 e4m3, fragment-permuted ----------------
// For 32x32x16 fp8 MFMA: lane l holds row/col (l&31), k = ks*16 + (l>>5)*8 + j.
// Store byte (row,k) at row*128 + ((k>>3)&1)*64 + (k>>4)*8 + (k&7): each lane's
// whole 8-MFMA fragment (64 bytes) is contiguous.
__global__ __launch_bounds__(256) void knorm(const float* __restrict__ t,
                                             unsigned char* __restrict__ bnq) {
    const int row  = blockIdx.x * 4 + (threadIdx.x >> 6);
    const int lane = threadIdx.x & 63;
    const float2 v = *(const float2*)(t + (size_t)row * D + lane * 2);
    float ss = v.x * v.x + v.y * v.y;
#pragma unroll
    for (int m = 1; m <= 32; m <<= 1) ss += __shfl_xor(ss, m, 64);
    const float inv = rsqrtf(ss);
    const int k   = lane * 2;
    const int off = ((k >> 3) & 1) * 64 + (k >> 4) * 8 + (k & 7);
    const unsigned bits =
        (unsigned)__builtin_amdgcn_cvt_pk_fp8_f32(v.x * inv, v.y * inv, 0, false);
    *(unsigned short*)(bnq + (size_t)row * 128 + off) = (unsigned short)(bits & 0xFFFFu);
}

// ---------------- Kernel B: fused fp8 bn @ bn^T (32x32x16) + group-argmax ----------------
// R12 geometry (512 blocks x 4 waves, no LDS/barriers, XCD decode), ONE change:
// the MFMA loop is ks-outer / c4-inner with 4 live accumulators (ILP-4), so
// consecutive MFMAs are data-independent and the matrix pipe is fed at issue
// rate instead of stalling on the 8-deep dependent acc chain (R12: MfmaUtil 52%).
__global__ __launch_bounds__(256, 2) void kargmax(const unsigned char* __restrict__ bnq,
                                                  float* __restrict__ pval,
                                                  int* __restrict__ pcode) {
    const int tid  = threadIdx.x;
    const int lane = tid & 63;
    const int w    = tid >> 6;
    const int b    = blockIdx.x;
    const int s    = (b & 7) * 2 + ((b >> 3) & 1);   // 2 splits per XCD
    const int ct   = b >> 4;                          // 0..31
    const int j0w  = ct * 512 + w * 128;
    const int rbase = s * ROWS_PER_SPLIT;

    const int cl = lane & 31;      // row/col within 32
    const int hi = lane >> 5;      // k-half
    const int rloc = cl - 4 * hi;  // diag helper: diag when rloc == (r&3)+8*(r>>2)

    // persistent B fragments: 128 cols x 128 K, fp8 (4 col-tiles x 8 K-steps, 64 VGPRs)
    i64 fb[4][8];
#pragma unroll
    for (int c4 = 0; c4 < 4; ++c4)
#pragma unroll
        for (int ks = 0; ks < 8; ++ks)
            fb[c4][ks] = *(const i64*)(bnq + (size_t)(j0w + c4 * 32 + cl) * 128 +
                                       hi * 64 + ks * 8);

    const unsigned char* aptr = bnq + (size_t)(rbase + cl) * 128 + hi * 64;

    float mv[4];
#pragma unroll
    for (int c4 = 0; c4 < 4; ++c4) mv[c4] = -1e30f;
    unsigned gb = (unsigned)hi;        // gid = gb + 2*g; gb += 8 per iter (max 255)

    const f32x16 z16 = {0.f,0.f,0.f,0.f,0.f,0.f,0.f,0.f,0.f,0.f,0.f,0.f,0.f,0.f,0.f,0.f};
    i64x2 fA[4], fB[4];

#define LOADF(buf, itv) do {                                  \
    const unsigned char* p_ = aptr + (size_t)(itv) * 4096;    \
    buf[0] = *(const i64x2*)(p_);                             \
    buf[1] = *(const i64x2*)(p_ + 16);                        \
    buf[2] = *(const i64x2*)(p_ + 32);                        \
    buf[3] = *(const i64x2*)(p_ + 48); } while (0)

#define COMPUTEF(buf, itv) do {                                                             \
    const int r0_ = rbase + (itv) * 32;                                                     \
    const bool dg_ = ((unsigned)(r0_ - j0w) < 128u);                                        \
    f32x16 acc[4];                                                                          \
    __builtin_amdgcn_s_setprio(1);                                                          \
    _Pragma("unroll")                                                                       \
    for (int c4 = 0; c4 < 4; ++c4)                                                          \
        acc[c4] = __builtin_amdgcn_mfma_f32_32x32x16_fp8_fp8(buf[0][0], fb[c4][0], z16, 0, 0, 0); \
    _Pragma("unroll")                                                                       \
    for (int ks = 1; ks < 8; ++ks) {                                                        \
        _Pragma("unroll")                                                                   \
        for (int c4 = 0; c4 < 4; ++c4)                                                      \
            acc[c4] = __builtin_amdgcn_mfma_f32_32x32x16_fp8_fp8(                           \
                buf[ks >> 1][ks & 1], fb[c4][ks], acc[c4], 0, 0, 0);                        \
    }                                                                                       \
    __builtin_amdgcn_s_setprio(0);                                                          \
    if (dg_) {                                                                              \
        _Pragma("unroll")                                                                   \
        for (int c4 = 0; c4 < 4; ++c4)                                                      \
            if (r0_ == j0w + c4 * 32) {                                                     \
                _Pragma("unroll")                                                           \
                for (int r = 0; r < 16; ++r)                                                \
                    if (rloc == ((r & 3) + 8 * (r >> 2))) acc[c4][r] -= 1.0f;               \
            }                                                                               \
    }                                                                                       \
    _Pragma("unroll")                                                                       \
    for (int c4 = 0; c4 < 4; ++c4) {                                                        \
        _Pragma("unroll")                                                                   \
        for (int g = 0; g < 4; ++g) {                                                       \
            const float g_ = fmaxf(fmaxf(acc[c4][4*g], acc[c4][4*g+1]),                     \
                                   fmaxf(acc[c4][4*g+2], acc[c4][4*g+3]));                  \
            const unsigned p_ = (__float_as_uint(g_) & 0xFFFFFF00u) | (gb + 2u * g);        \
            mv[c4] = fmaxf(mv[c4], __uint_as_float(p_));                                    \
        }                                                                                   \
    }                                                                                       \
    gb += 8u; } while (0)

    LOADF(fA, 0);
    LOADF(fB, 1);
    for (int it2 = 0; it2 < ITERS; it2 += 2) {
        COMPUTEF(fA, it2);     LOADF(fA, it2 + 2);   // overshoot -> pval pad, unused
        COMPUTEF(fB, it2 + 1); LOADF(fB, it2 + 3);
    }
#undef LOADF
#undef COMPUTEF

    // lanes l and l+32 share col cl: one packed fmax merges the k-halves
#pragma unroll
    for (int c4 = 0; c4 < 4; ++c4) {
        float v = mv[c4];
        v = fmaxf(v, __shfl_xor(v, 32, 64));
        if (lane < 32) {
            pval[(size_t)s * N + j0w + c4 * 32 + cl]  = v;
            pcode[(size_t)s * N + j0w + c4 * 32 + cl] =
                rbase + (int)(__float_as_uint(v) & 255u) * 4;
        }
    }
}

// ---------------- Kernel C: merge splits, re-rank 4 candidates in fp32, hinge ----------------
__global__ __launch_bounds__(256) void kloss(const float* __restrict__ q,
                                             const float* __restrict__ t,
                                             const float* __restrict__ pval,
                                             const int* __restrict__ pcode,
                                             float* __restrict__ bsum) {
    const int j    = blockIdx.x * 4 + (threadIdx.x >> 6);
    const int lane = threadIdx.x & 63;

    // merge the RS split winners (lane s holds split s)
    float v = -1e30f;
    int   c = 0;
    if (lane < RS) { v = pval[(size_t)lane * N + j]; c = pcode[(size_t)lane * N + j]; }
#pragma unroll
    for (int m = 1; m <= 8; m <<= 1) {
        const float ov = __shfl_xor(v, m, 64);
        const int   oc = __shfl_xor(c, m, 64);
        if (ov > v || (ov == v && oc < c)) { v = ov; c = oc; }
    }
    c = __shfl(c, 0, 64);

    const float2 qv = *(const float2*)(q + (size_t)j * D + lane * 2);
    const float2 tv = *(const float2*)(t + (size_t)j * D + lane * 2);
    float qq = qv.x * qv.x + qv.y * qv.y;
    float tt = tv.x * tv.x + tv.y * tv.y;
    float qt = qv.x * tv.x + qv.y * tv.y;
    float ww[4], wt[4], qw[4];
#pragma unroll
    for (int r = 0; r < 4; ++r) {
        const float2 wv = *(const float2*)(t + (size_t)(c + r) * D + lane * 2);
        ww[r] = wv.x * wv.x + wv.y * wv.y;
        wt[r] = wv.x * tv.x + wv.y * tv.y;
        qw[r] = wv.x * qv.x + wv.y * qv.y;
    }
#pragma unroll
    for (int m = 1; m <= 32; m <<= 1) {
        qq += __shfl_xor(qq, m, 64);
        tt += __shfl_xor(tt, m, 64);
        qt += __shfl_xor(qt, m, 64);
#pragma unroll
        for (int r = 0; r < 4; ++r) {
            ww[r] += __shfl_xor(ww[r], m, 64);
            wt[r] += __shfl_xor(wt[r], m, 64);
            qw[r] += __shfl_xor(qw[r], m, 64);
        }
    }
    const float pos = qt * rsqrtf(qq * tt);
    float best = -1e30f, neg = 0.f;
#pragma unroll
    for (int r = 0; r < 4; ++r) {
        float cr = wt[r] * rsqrtf(ww[r] * tt);
        if (c + r == j) cr -= 1.0f;              // diag candidate, matches sim - eye
        if (cr > best) { best = cr; neg = qw[r] * rsqrtf(qq * ww[r]); }
    }
    const float l = fmaxf(0.f, 1.0f - pos + neg);

    __shared__ float ls[4];
    if (lane == 0) ls[threadIdx.x >> 6] = l;
    __syncthreads();
    if (threadIdx.x == 0) bsum[blockIdx.x] = ls[0] + ls[1] + ls[2] + ls[3];
}

// ---------------- Kernel D: deterministic final mean ----------------
__global__ __launch_bounds__(256) void kfinal(const float* __restrict__ bsum,
                                              float* __restrict__ out) {
    float sum = 0.f;
    for (int i = threadIdx.x; i < N / 4; i += 256) sum += bsum[i];
#pragma unroll
    for (int m = 1; m <= 32; m <<= 1) sum += __shfl_xor(sum, m, 64);
    __shared__ float ws2[4];
    if ((threadIdx.x & 63) == 0) ws2[threadIdx.x >> 6] = sum;
    __syncthreads();
    if (threadIdx.x == 0) out[0] = (ws2[0] + ws2[1] + ws2[2] + ws2[3]) * (1.0f / N);
}

extern "C" void kernel_launch(void* const* d_in, const int* in_sizes, int n_in,
                              void* d_out, int out_size, void* d_ws, size_t ws_size,
                              hipStream_t stream) {
    const float* q = (const float*)d_in[0];
    const float* t = (const float*)d_in[1];
    char* ws = (char*)d_ws;

    unsigned char* bnq = (unsigned char*)ws;                           // 2 MB (must stay first)
    float* pval = (float*)(ws + (size_t)N * 128);                      // 1 MB (also overshoot pad)
    int*   pcode = (int*)(ws + (size_t)N * 128 + (size_t)RS * N * 4);  // 1 MB
    float* bsum = (float*)(ws + (size_t)N * 128 + (size_t)2 * RS * N * 4); // 16 KB

    knorm<<<dim3(N / 4), dim3(256), 0, stream>>>(t, bnq);
    kargmax<<<dim3(CT * RS), dim3(256), 0, stream>>>(bnq, pval, pcode);
    kloss<<<dim3(N / 4), dim3(256), 0, stream>>>(q, t, pval, pcode, bsum);
    kfinal<<<dim3(1), dim3(256), 0, stream>>>(bsum, (float*)d_out);
}

// Round 16
// 71.150 us; speedup vs baseline: 7.9433x; 1.1004x over previous
//
#include <hip/hip_runtime.h>
#include <hip/hip_bf16.h>

#define N 16384
#define D 128
#define RS 16                        // row splits (1024 rows each)
#define CT 32                        // col tiles (N / 512)
#define ROWS_PER_SPLIT (N / RS)      // 1024
#define ITERS (ROWS_PER_SPLIT / 32)  // 32 iterations of 32 rows

typedef __attribute__((ext_vector_type(4))) int i32x4;
typedef __attribute__((ext_vector_type(16))) int i32x16;

// ---------------- Kernel A: normalize targets -> int8 (scale 127), row-major ----------------
// For 32x32x32 i8 MFMA, lane l covers row/col (l&31) with k = ks*32 + (l>>5)*16 + j,
// j=0..15 — 16 CONTIGUOUS bytes: plain row-major i8 needs no permutation.
__global__ __launch_bounds__(256) void knorm(const float* __restrict__ t,
                                             char* __restrict__ bnq) {
    const int row  = blockIdx.x * 4 + (threadIdx.x >> 6);
    const int lane = threadIdx.x & 63;
    const float2 v = *(const float2*)(t + (size_t)row * D + lane * 2);
    float ss = v.x * v.x + v.y * v.y;
#pragma unroll
    for (int m = 1; m <= 32; m <<= 1) ss += __shfl_xor(ss, m, 64);
    const float inv = rsqrtf(ss) * 127.0f;
    char2 o;
    o.x = (char)__float2int_rn(v.x * inv);
    o.y = (char)__float2int_rn(v.y * inv);
    *(char2*)(bnq + (size_t)row * 128 + lane * 2) = o;
}

// ---------------- Kernel B: fused i8 bn @ bn^T (32x32x32) + group-argmax ----------------
// R12 geometry (512 blocks x 4 waves, no LDS/barriers, XCD decode), i8 MFMA:
// K=32 per instruction -> 1.05M MFMA total (half of fp8 K=16). int32 sims are
// EXACT; argmax packs (sim<<8)+gid in one int (v_lshl_add + v_max_i32).
// Diagonal excluded by subtracting 2^30 (max off-diag sim is always positive here).
__global__ __launch_bounds__(256, 2) void kargmax(const char* __restrict__ bnq,
                                                  int* __restrict__ pval,
                                                  int* __restrict__ pcode) {
    const int tid  = threadIdx.x;
    const int lane = tid & 63;
    const int w    = tid >> 6;
    const int b    = blockIdx.x;
    const int s    = (b & 7) * 2 + ((b >> 3) & 1);   // 2 splits per XCD
    const int ct   = b >> 4;                          // 0..31
    const int j0w  = ct * 512 + w * 128;
    const int rbase = s * ROWS_PER_SPLIT;

    const int cl = lane & 31;      // row/col within 32
    const int hi = lane >> 5;      // k-half
    const int rloc = cl - 4 * hi;  // diag helper: diag when rloc == (r&3)+8*(r>>2)

    // persistent B fragments: 128 cols x 128 K, i8 (4 col-tiles x 4 K-steps, 64 VGPRs)
    i32x4 fb[4][4];
#pragma unroll
    for (int c4 = 0; c4 < 4; ++c4)
#pragma unroll
        for (int ks = 0; ks < 4; ++ks)
            fb[c4][ks] = *(const i32x4*)(bnq + (size_t)(j0w + c4 * 32 + cl) * 128 +
                                         ks * 32 + hi * 16);

    const char* aptr = bnq + (size_t)(rbase + cl) * 128 + hi * 16;

    int mv[4];
#pragma unroll
    for (int c4 = 0; c4 < 4; ++c4) mv[c4] = INT_MIN;
    int gb = hi;                       // gid = gb + 2*g; gb += 8 per iter (max 255)

    const i32x16 z16 = {0,0,0,0,0,0,0,0,0,0,0,0,0,0,0,0};
    i32x4 fA[4], fB[4];

#define LOADF(buf, itv) do {                                  \
    const char* p_ = aptr + (size_t)(itv) * 4096;             \
    buf[0] = *(const i32x4*)(p_);                             \
    buf[1] = *(const i32x4*)(p_ + 32);                        \
    buf[2] = *(const i32x4*)(p_ + 64);                        \
    buf[3] = *(const i32x4*)(p_ + 96); } while (0)

#define COMPUTEF(buf, itv) do {                                                             \
    const int r0_ = rbase + (itv) * 32;                                                     \
    const bool dg_ = ((unsigned)(r0_ - j0w) < 128u);                                        \
    i32x16 acc[4];                                                                          \
    __builtin_amdgcn_s_setprio(1);                                                          \
    _Pragma("unroll")                                                                       \
    for (int c4 = 0; c4 < 4; ++c4)                                                          \
        acc[c4] = __builtin_amdgcn_mfma_i32_32x32x32_i8(buf[0], fb[c4][0], z16, 0, 0, 0);   \
    _Pragma("unroll")                                                                       \
    for (int ks = 1; ks < 4; ++ks) {                                                        \
        _Pragma("unroll")                                                                   \
        for (int c4 = 0; c4 < 4; ++c4)                                                      \
            acc[c4] = __builtin_amdgcn_mfma_i32_32x32x32_i8(buf[ks], fb[c4][ks],            \
                                                            acc[c4], 0, 0, 0);              \
    }                                                                                       \
    __builtin_amdgcn_s_setprio(0);                                                          \
    if (dg_) {                                                                              \
        _Pragma("unroll")                                                                   \
        for (int c4 = 0; c4 < 4; ++c4)                                                      \
            if (r0_ == j0w + c4 * 32) {                                                     \
                _Pragma("unroll")                                                           \
                for (int r = 0; r < 16; ++r)                                                \
                    if (rloc == ((r & 3) + 8 * (r >> 2))) acc[c4][r] -= (1 << 30);          \
            }                                                                               \
    }                                                                                       \
    _Pragma("unroll")                                                                       \
    for (int c4 = 0; c4 < 4; ++c4) {                                                        \
        _Pragma("unroll")                                                                   \
        for (int g = 0; g < 4; ++g) {                                                       \
            const int m_ = max(max(acc[c4][4*g], acc[c4][4*g+1]),                           \
                               max(acc[c4][4*g+2], acc[c4][4*g+3]));                        \
            const int p_ = (int)(((unsigned)m_ << 8)) + (gb + 2 * g);                       \
            mv[c4] = max(mv[c4], p_);                                                       \
        }                                                                                   \
    }                                                                                       \
    gb += 8; } while (0)

    LOADF(fA, 0);
    LOADF(fB, 1);
    for (int it2 = 0; it2 < ITERS; it2 += 2) {
        COMPUTEF(fA, it2);     LOADF(fA, it2 + 2);   // overshoot -> pval pad, unused
        COMPUTEF(fB, it2 + 1); LOADF(fB, it2 + 3);
    }
#undef LOADF
#undef COMPUTEF

    // lanes l and l+32 hold different row-halves of each column: one max merges them
#pragma unroll
    for (int c4 = 0; c4 < 4; ++c4) {
        int v = mv[c4];
        v = max(v, __shfl_xor(v, 32, 64));
        if (lane < 32) {
            pval[(size_t)s * N + j0w + c4 * 32 + cl]  = v;
            pcode[(size_t)s * N + j0w + c4 * 32 + cl] = rbase + (v & 255) * 4;
        }
    }
}

// ---------------- Kernel C: merge splits, re-rank 4 candidates in fp32, hinge ----------------
__global__ __launch_bounds__(256) void kloss(const float* __restrict__ q,
                                             const float* __restrict__ t,
                                             const int* __restrict__ pval,
                                             const int* __restrict__ pcode,
                                             float* __restrict__ bsum) {
    const int j    = blockIdx.x * 4 + (threadIdx.x >> 6);
    const int lane = threadIdx.x & 63;

    // merge the RS split winners (lane s holds split s); packed ints compare directly
    int v = INT_MIN;
    int c = 0;
    if (lane < RS) { v = pval[(size_t)lane * N + j]; c = pcode[(size_t)lane * N + j]; }
#pragma unroll
    for (int m = 1; m <= 8; m <<= 1) {
        const int ov = __shfl_xor(v, m, 64);
        const int oc = __shfl_xor(c, m, 64);
        if (ov > v || (ov == v && oc < c)) { v = ov; c = oc; }
    }
    c = __shfl(c, 0, 64);

    const float2 qv = *(const float2*)(q + (size_t)j * D + lane * 2);
    const float2 tv = *(const float2*)(t + (size_t)j * D + lane * 2);
    float qq = qv.x * qv.x + qv.y * qv.y;
    float tt = tv.x * tv.x + tv.y * tv.y;
    float qt = qv.x * tv.x + qv.y * tv.y;
    float ww[4], wt[4], qw[4];
#pragma unroll
    for (int r = 0; r < 4; ++r) {
        const float2 wv = *(const float2*)(t + (size_t)(c + r) * D + lane * 2);
        ww[r] = wv.x * wv.x + wv.y * wv.y;
        wt[r] = wv.x * tv.x + wv.y * tv.y;
        qw[r] = wv.x * qv.x + wv.y * qv.y;
    }
#pragma unroll
    for (int m = 1; m <= 32; m <<= 1) {
        qq += __shfl_xor(qq, m, 64);
        tt += __shfl_xor(tt, m, 64);
        qt += __shfl_xor(qt, m, 64);
#pragma unroll
        for (int r = 0; r < 4; ++r) {
            ww[r] += __shfl_xor(ww[r], m, 64);
            wt[r] += __shfl_xor(wt[r], m, 64);
            qw[r] += __shfl_xor(qw[r], m, 64);
        }
    }
    const float pos = qt * rsqrtf(qq * tt);
    float best = -1e30f, neg = 0.f;
#pragma unroll
    for (int r = 0; r < 4; ++r) {
        float cr = wt[r] * rsqrtf(ww[r] * tt);
        if (c + r == j) cr -= 1.0f;              // diag candidate, matches sim - eye
        if (cr > best) { best = cr; neg = qw[r] * rsqrtf(qq * ww[r]); }
    }
    const float l = fmaxf(0.f, 1.0f - pos + neg);

    __shared__ float ls[4];
    if (lane == 0) ls[threadIdx.x >> 6] = l;
    __syncthreads();
    if (threadIdx.x == 0) bsum[blockIdx.x] = ls[0] + ls[1] + ls[2] + ls[3];
}

// ---------------- Kernel D: deterministic final mean ----------------
__global__ __launch_bounds__(256) void kfinal(const float* __restrict__ bsum,
                                              float* __restrict__ out) {
    float sum = 0.f;
    for (int i = threadIdx.x; i < N / 4; i += 256) sum += bsum[i];
#pragma unroll
    for (int m = 1; m <= 32; m <<= 1) sum += __shfl_xor(sum, m, 64);
    __shared__ float ws2[4];
    if ((threadIdx.x & 63) == 0) ws2[threadIdx.x >> 6] = sum;
    __syncthreads();
    if (threadIdx.x == 0) out[0] = (ws2[0] + ws2[1] + ws2[2] + ws2[3]) * (1.0f / N);
}

extern "C" void kernel_launch(void* const* d_in, const int* in_sizes, int n_in,
                              void* d_out, int out_size, void* d_ws, size_t ws_size,
                              hipStream_t stream) {
    const float* q = (const float*)d_in[0];
    const float* t = (const float*)d_in[1];
    char* ws = (char*)d_ws;

    char* bnq = ws;                                                    // 2 MB (must stay first)
    int*  pval = (int*)(ws + (size_t)N * 128);                         // 1 MB (also overshoot pad)
    int*  pcode = (int*)(ws + (size_t)N * 128 + (size_t)RS * N * 4);   // 1 MB
    float* bsum = (float*)(ws + (size_t)N * 128 + (size_t)2 * RS * N * 4); // 16 KB

    knorm<<<dim3(N / 4), dim3(256), 0, stream>>>(t, bnq);
    kargmax<<<dim3(CT * RS), dim3(256), 0, stream>>>(bnq, pval, pcode);
    kloss<<<dim3(N / 4), dim3(256), 0, stream>>>(q, t, pval, pcode, bsum);
    kfinal<<<dim3(1), dim3(256), 0, stream>>>(bsum, (float*)d_out);
}